// Round 21
// baseline (18.260 us; speedup 1.0000x reference)
//
#include <hip/hip_runtime.h>

// MosaicSDF: N=1024 points, G=512 grids, K=7 (343 nodes/grid).
// R21 = R18 with COALESCED node-major lane assignment. Every prior
// variant loaded rows with lane-stride 28B (~28 L1 lines per wave load
// instr = the stubborn ~13us floor term). Fix: 32-lane groups, lane sub
// owns nodes c = sub+32k (stride 4B across lanes -> 2-3 lines per group
// instr). The (i,j,l) node coords are pair-invariant per (lane,k):
// hoisted ONCE before the drain loop into CX/CY/CZ[11] (static-unroll
// indexing -> registers). Invalid (sub>22,k=10) slots: far coords (wt=0)
// + clamped in-row address. 5-step group reduce (xor<=16 stays in the
// 32-lane half).
//   Phase 1 (R18 verbatim): wave w sweeps 128 grids for point w>>2;
//     ballot-scan compacts (rx,ry,rz,gwr)+gid per wave segment.
//   Phase 2: 16 32-lane groups drain pooled actives (CT=C0+C1) direct
//     from L2; acc0/acc1 by segment. No atomics, no workspace, one
//     dispatch, ~18.4KB LDS -> 4 blocks/CU.

#define NPTS   1024
#define NGRIDS 512
#define TPB    512
#define NBLK   512             // 2 points per block
#define STEP   (1.0f / 6.0f)
#define FSQRT(x) __builtin_amdgcn_sqrtf(x)

__global__ __launch_bounds__(TPB, 4) void msdf_fused(
    const float* __restrict__ points,    // (N,3)
    const float* __restrict__ centers,   // (G,3)
    const float* __restrict__ scales,    // (G,)
    const float* __restrict__ vals,      // (G,343)
    float* __restrict__ out)             // (N,)
{
    __shared__ float4 s_pair[8][128];         // 16,384 B (rx,ry,rz,gwr)
    __shared__ unsigned short s_gid[8][128];  // 2,048 B
    __shared__ int   s_c[8];
    __shared__ float s_d[8];
    __shared__ float s_red[8][2];

    const int bid  = blockIdx.x;
    const int t    = threadIdx.x;
    const int w    = t >> 6;             // wave 0..7
    const int lane = t & 63;
    const int grp  = t >> 5;             // 0..15: 32-lane group (pair slot)
    const int sub  = t & 31;

    const int   n  = (bid << 1) + (w >> 2);  // this wave's point
    const float px = points[n * 3 + 0];      // wave-uniform -> scalar loads
    const float py = points[n * 3 + 1];
    const float pz = points[n * 3 + 2];

    // ---- Phase 1: activity sweep + ballot-scan compaction ----
    float dsum  = 0.0f;
    int   cbase = 0;
    #pragma unroll
    for (int r = 0; r < 2; ++r) {
        const int g = ((w & 3) << 7) + (r << 6) + lane;  // wave's 128 grids
        const float invs = 1.0f / scales[g];
        const float rx = (px - centers[g * 3 + 0]) * invs;
        const float ry = (py - centers[g * 3 + 1]) * invs;
        const float rz = (pz - centers[g * 3 + 2]) * invs;
        const float gwr = 1.0f - FSQRT(rx * rx + ry * ry + rz * rz);
        const bool  act = (gwr > 0.0f);
        const unsigned long long m = __ballot(act);
        if (act) {
            const int pos = cbase + (int)__popcll(m & ((1ull << lane) - 1ull));
            s_pair[w][pos] = make_float4(rx, ry, rz, gwr);
            s_gid[w][pos]  = (unsigned short)g;
            dsum += gwr;
        }
        cbase += (int)__popcll(m);
    }
    #pragma unroll
    for (int o = 32; o >= 1; o >>= 1) dsum += __shfl_xor(dsum, o);
    if (lane == 0) { s_c[w] = cbase; s_d[w] = dsum; }
    __syncthreads();

    const int o1 = s_c[0];
    const int o2 = o1 + s_c[1];
    const int o3 = o2 + s_c[2];
    const int o4 = o3 + s_c[3];
    const int o5 = o4 + s_c[4];
    const int o6 = o5 + s_c[5];
    const int o7 = o6 + s_c[6];
    const int CT = o7 + s_c[7];
    const float den0 = s_d[0] + s_d[1] + s_d[2] + s_d[3];
    const float den1 = s_d[4] + s_d[5] + s_d[6] + s_d[7];

    // ---- Hoist per-(lane,k) node coords: c = sub + 32k, k = 0..10 ----
    float CX[11], CY[11], CZ[11];
    int   CA[11];                        // clamped in-row load address
    #pragma unroll
    for (int k = 0; k < 11; ++k) {
        const int c     = sub + (k << 5);
        const bool okc  = (c <= 342);
        const int  cc   = okc ? c : 342;
        const int  i    = (cc * 1338) >> 16;           // cc / 49
        const int  rem  = cc - i * 49;
        const int  j    = (rem * 9363) >> 16;          // rem / 7
        const int  l    = rem - j * 7;
        CX[k] = okc ? (float)i * STEP : 99.0f;         // far -> wt = 0
        CY[k] = okc ? (float)j * STEP : 99.0f;
        CZ[k] = okc ? (float)l * STEP : 99.0f;
        CA[k] = cc;
    }

    // ---- Phase 2: 16 32-lane groups, coalesced direct-from-L2 ----
    float acc0 = 0.0f, acc1 = 0.0f;
    for (int a = grp; a < CT; a += 16) {
        const int seg = (a >= o1) + (a >= o2) + (a >= o3) + (a >= o4)
                      + (a >= o5) + (a >= o6) + (a >= o7);
        const int b0  = (seg == 0) ? 0 : (seg == 1) ? o1
                      : (seg == 2) ? o2 : (seg == 3) ? o3
                      : (seg == 4) ? o4 : (seg == 5) ? o5
                      : (seg == 6) ? o6 : o7;
        const float4 pr  = s_pair[seg][a - b0];
        const int    gid = (int)s_gid[seg][a - b0];
        const float* __restrict__ grow = vals + gid * 343;

        float ws = 0.0f, vs = 0.0f;
        #pragma unroll
        for (int k = 0; k < 11; ++k) {
            const float v  = grow[CA[k]];            // lane-stride 4B: coalesced
            const float dx = pr.x - CX[k];
            const float dy = pr.y - CY[k];
            const float dz = pr.z - CZ[k];
            const float d2 = fmaf(dx, dx, fmaf(dy, dy, dz * dz));
            const float wt = (d2 <= 1.0f) ? FSQRT(d2) : 0.0f;
            ws += wt;
            vs  = fmaf(wt, v, vs);
        }
        #pragma unroll
        for (int o = 16; o >= 1; o >>= 1) {          // stays in 32-lane half
            ws += __shfl_xor(ws, o);
            vs += __shfl_xor(vs, o);
        }
        const float interp = (ws > 0.0f) ? (vs / ws) : 0.0f;
        if (sub == 0) {
            const float contrib = interp * pr.w;
            if (seg < 4) acc0 += contrib;
            else         acc1 += contrib;
        }
    }

    // Block reduction: butterfly per wave, then cross-wave via LDS.
    #pragma unroll
    for (int o = 32; o >= 1; o >>= 1) {
        acc0 += __shfl_xor(acc0, o);
        acc1 += __shfl_xor(acc1, o);
    }
    if (lane == 0) { s_red[w][0] = acc0; s_red[w][1] = acc1; }
    __syncthreads();
    if (t < 2) {
        float nm = 0.0f;
        #pragma unroll
        for (int i = 0; i < 8; ++i) nm += s_red[i][t];
        const float dn = (t == 0) ? den0 : den1;
        out[(bid << 1) + t] = (dn > 0.0f) ? (nm / dn) : 0.0f;
    }
}

extern "C" void kernel_launch(void* const* d_in, const int* in_sizes, int n_in,
                              void* d_out, int out_size, void* d_ws, size_t ws_size,
                              hipStream_t stream) {
    const float* points  = (const float*)d_in[0];   // (1024,3)
    const float* centers = (const float*)d_in[1];   // (512,3)
    const float* scales  = (const float*)d_in[2];   // (512,)
    const float* vals    = (const float*)d_in[3];   // (512,7,7,7)
    float* out = (float*)d_out;                     // (1024,)

    msdf_fused<<<NBLK, TPB, 0, stream>>>(points, centers, scales, vals, out);
}